// Round 2
// baseline (246.701 us; speedup 1.0000x reference)
//
#include <hip/hip_runtime.h>

#define ALG_DIM 248
#define ROWS 16                    // rows per main-kernel block
#define KSPLIT 4
#define KPB (ALG_DIM / KSPLIT)     // 62 k-buckets per block
#define QUADS 4                    // row-quads per stream (ROWS/4)
#define NSTREAMS 64                // 256 threads / 4 quad-lanes

// ---------- prep: ONE single-block kernel buckets triples by idx_k ----------
// count (LDS atomics) -> exclusive scan (LDS) -> scatter with LDS cursors.
// ws re-poisoned to 0xAA every launch, so everything is recomputed here.

__global__ __launch_bounds__(1024) void k_prep(
    const int* __restrict__ idx_i, const int* __restrict__ idx_j,
    const int* __restrict__ idx_k, const float* __restrict__ coeff,
    int* __restrict__ offs /*256 ints*/, uint2* __restrict__ packed, int nnz)
{
    __shared__ int cnt[256];    // counts, then cursors
    __shared__ int scan[256];
    const int tid = threadIdx.x;

    if (tid < 256) cnt[tid] = 0;
    __syncthreads();

    for (int t = tid; t < nnz; t += 1024)
        atomicAdd(&cnt[idx_k[t]], 1);
    __syncthreads();

    int v = 0;
    if (tid < 256) { v = cnt[tid]; scan[tid] = v; }
    __syncthreads();
    for (int off = 1; off < 256; off <<= 1) {
        int add = 0;
        if (tid < 256 && tid >= off) add = scan[tid - off];
        __syncthreads();
        if (tid < 256) scan[tid] += add;
        __syncthreads();
    }
    if (tid < 256) {
        int ex = scan[tid] - v;    // exclusive prefix
        cnt[tid]  = ex;            // becomes cursor
        offs[tid] = ex;            // offs[k]..offs[k+1] valid for k<248 since counts 248..255 are 0
    }
    __syncthreads();

    for (int t = tid; t < nnz; t += 1024) {
        int k = idx_k[t];
        int pos = atomicAdd(&cnt[k], 1);
        uint2 p;
        p.x = (unsigned)idx_i[t] | ((unsigned)idx_j[t] << 16);
        p.y = __float_as_uint(coeff[t]);
        packed[pos] = p;
    }
}

// ---------- main: bucketed gather-multiply-accumulate, no atomics ----------
// Block: 256 threads = 64 streams x 4 row-quads over 16 rows x 62 k-buckets.
// x,y staged in LDS column-major [248][16] (31 KB total -> 5 blocks/CU,
// 20 waves/CU). Each lane's 4-row gather is one ds_read_b128. Inner loop is
// software-pipelined: packed[t+2] and the LDS reads for t+1 issue before the
// FMAs for t, so the ~120cyc LDS latency is hidden behind one iteration.

__global__ __launch_bounds__(256, 5) void k_main(
    const float* __restrict__ x, const float* __restrict__ y,
    const int* __restrict__ offs, const uint2* __restrict__ packed,
    const float* __restrict__ alpha_p, float* __restrict__ out)
{
    __shared__ __align__(16) float xs[ALG_DIM * ROWS];
    __shared__ __align__(16) float ys[ALG_DIM * ROWS];

    const int tid   = threadIdx.x;
    const int r0    = blockIdx.x * ROWS;
    const int kbase = blockIdx.y * KPB;

    // Stage x,y -> LDS column-major: xs[i*16 + r]. Consecutive u -> consecutive
    // LDS addresses (conflict-free writes).
    for (int u = tid; u < ALG_DIM * ROWS; u += 256) {
        int i = u >> 4;
        int r = u & 15;
        xs[u] = x[(size_t)(r0 + r) * ALG_DIM + i];
        ys[u] = y[(size_t)(r0 + r) * ALG_DIM + i];
    }
    __syncthreads();

    const float alpha = alpha_p[0];
    const int S  = tid >> 2;       // stream id 0..63, owns one k-bucket
    const int q  = tid & 3;        // row-quad 0..3 (rows 4q..4q+3)
    const int qo = q << 2;

    if (S < KPB) {
        const int k  = kbase + S;
        const int ts = offs[k];
        const int te = offs[k + 1];

        float4 acc = make_float4(0.f, 0.f, 0.f, 0.f);

        if (ts < te) {
            uint2 pA = packed[ts];
            uint2 pB = (ts + 1 < te) ? packed[ts + 1] : pA;
            float4 xvA = *reinterpret_cast<const float4*>(&xs[((pA.x & 0xFFFFu) << 4) + qo]);
            float4 yvA = *reinterpret_cast<const float4*>(&ys[((pA.x >> 16) << 4) + qo]);

            for (int t = ts; t < te; ++t) {
                // issue next triple's LDS reads + packed prefetch BEFORE using current
                float4 xvB = *reinterpret_cast<const float4*>(&xs[((pB.x & 0xFFFFu) << 4) + qo]);
                float4 yvB = *reinterpret_cast<const float4*>(&ys[((pB.x >> 16) << 4) + qo]);
                uint2 pC = (t + 2 < te) ? packed[t + 2] : pB;

                const float c = __uint_as_float(pA.y);
                acc.x = fmaf(xvA.x * yvA.x, c, acc.x);
                acc.y = fmaf(xvA.y * yvA.y, c, acc.y);
                acc.z = fmaf(xvA.z * yvA.z, c, acc.z);
                acc.w = fmaf(xvA.w * yvA.w, c, acc.w);

                pA = pB; pB = pC; xvA = xvB; yvA = yvB;
            }
        }

        const int rbase = r0 + qo;
        out[(size_t)(rbase + 0) * ALG_DIM + k] = alpha * acc.x;
        out[(size_t)(rbase + 1) * ALG_DIM + k] = alpha * acc.y;
        out[(size_t)(rbase + 2) * ALG_DIM + k] = alpha * acc.z;
        out[(size_t)(rbase + 3) * ALG_DIM + k] = alpha * acc.w;
    }
}

// ---------- launch ----------

extern "C" void kernel_launch(void* const* d_in, const int* in_sizes, int n_in,
                              void* d_out, int out_size, void* d_ws, size_t ws_size,
                              hipStream_t stream) {
    const float* x      = (const float*)d_in[0];
    const float* y      = (const float*)d_in[1];
    const int*   idx_i  = (const int*)d_in[2];
    const int*   idx_j  = (const int*)d_in[3];
    const int*   idx_k  = (const int*)d_in[4];
    const float* coeff  = (const float*)d_in[5];
    const float* alpha  = (const float*)d_in[6];
    float*       out    = (float*)d_out;

    const int nnz   = in_sizes[2];
    const int batch = in_sizes[0] / ALG_DIM;

    // workspace layout: [offs 256 ints][packed nnz*uint2]
    char*  ws     = (char*)d_ws;
    int*   offs   = (int*)ws;
    uint2* packed = (uint2*)(ws + 256 * sizeof(int));

    k_prep<<<1, 1024, 0, stream>>>(idx_i, idx_j, idx_k, coeff, offs, packed, nnz);

    dim3 grid(batch / ROWS, KSPLIT);
    k_main<<<grid, 256, 0, stream>>>(x, y, offs, packed, alpha, out);
}

// Round 4
// 171.021 us; speedup vs baseline: 1.4425x; 1.4425x over previous
//
#include <hip/hip_runtime.h>

#define ALG_DIM 248
#define ROWS 16                    // rows per main-kernel block
#define KSPLIT 4
#define KPB (ALG_DIM / KSPLIT)     // 62 k-buckets per block
#define PMAX 1024                  // safety clamp for padded bucket length

// ---------- prep chain: bucket triples by idx_k into a PADDED matrix ----------
// packedP[k*P + t], t < P (uniform, multiple of 8). Pad entries have coeff=0.
// Index halves are PRE-SCALED to LDS byte offsets: lo16 = i*64, hi16 = j*64
// (64 = ROWS*4 bytes = column stride of the LDS layout).

__global__ void k_init(int* __restrict__ cnt) {
    int t = threadIdx.x;
    if (t < ALG_DIM) cnt[t] = 0;
}

__global__ void k_count(const int* __restrict__ idx_k, int* __restrict__ cnt, int nnz) {
    int t = blockIdx.x * blockDim.x + threadIdx.x;
    if (t < nnz) atomicAdd(&cnt[idx_k[t]], 1);
}

__global__ void k_meta(const int* __restrict__ cnt, int* __restrict__ meta,
                       int* __restrict__ cursor) {
    __shared__ int red[256];
    int t = threadIdx.x;
    int v = (t < ALG_DIM) ? cnt[t] : 0;
    red[t] = v;
    __syncthreads();
    for (int off = 128; off > 0; off >>= 1) {
        if (t < off) red[t] = max(red[t], red[t + off]);
        __syncthreads();
    }
    __shared__ int Ps;
    if (t == 0) {
        int P = (red[0] + 7) & ~7;           // multiple of 8
        P = max(P, 8);
        P = min(P, PMAX);                    // never overflow workspace
        meta[0] = P;
        Ps = P;
    }
    __syncthreads();
    if (t < ALG_DIM) cursor[t] = t * Ps;     // element index into packedP
}

__global__ void k_fill(uint2* __restrict__ packedP, const int* __restrict__ meta) {
    int P = meta[0];
    int total = ALG_DIM * P + 8;             // +8 slack for the tail over-read
    int stride = gridDim.x * blockDim.x;
    for (int t = blockIdx.x * blockDim.x + threadIdx.x; t < total; t += stride)
        packedP[t] = make_uint2(0u, 0u);     // i=j=0 (byte offset 0), coeff=0.0f
}

__global__ void k_scatter(const int* __restrict__ idx_i, const int* __restrict__ idx_j,
                          const int* __restrict__ idx_k, const float* __restrict__ coeff,
                          int* __restrict__ cursor, uint2* __restrict__ packedP,
                          const int* __restrict__ meta, int nnz) {
    int t = blockIdx.x * blockDim.x + threadIdx.x;
    if (t < nnz) {
        int k = idx_k[t];
        int P = meta[0];
        int pos = atomicAdd(&cursor[k], 1);
        if (pos < (k + 1) * P) {             // can only trip if P was clamped
            uint2 p;
            p.x = ((unsigned)idx_i[t] << 6) | ((unsigned)idx_j[t] << 22);
            p.y = __float_as_uint(coeff[t]);
            packedP[pos] = p;
        }
    }
}

// ---------- main: uniform-trip gather-multiply-accumulate ----------
// Block: 256 threads = 64 streams x 4 quad-lanes over 16 rows x 62 k-buckets.
// LDS column-major xs[i*16 + r] (31 KB total -> 5 blocks/CU). Lane's 4-row
// gather = one ds_read_b128. Trip count P is grid-uniform (padded), so the
// loop has NO bounds checks, NO cndmask, NO register rotation: just an
// unconditional next-chunk prefetch of 8 triples (4 x dwordx4).

__global__ __launch_bounds__(256, 5) void k_main(
    const float* __restrict__ x, const float* __restrict__ y,
    const uint4* __restrict__ packed4,       // packedP viewed as uint4 (2 triples)
    const int* __restrict__ meta,
    const float* __restrict__ alpha_p, float* __restrict__ out)
{
    __shared__ __align__(16) float xs[ALG_DIM * ROWS];
    __shared__ __align__(16) float ys[ALG_DIM * ROWS];

    const int tid = threadIdx.x;
    const int r0  = blockIdx.x * ROWS;

    // Coalesced staging: lane reads float4 along a row, scatters 4 floats into
    // column-major LDS. Write-bank conflicts here are bounded by total LDS
    // write bytes (31.7 KB/block) — negligible vs the gather loop.
    for (int u = tid; u < (ALG_DIM / 4) * ROWS; u += 256) {
        int r = u / (ALG_DIM / 4);
        int c = u - r * (ALG_DIM / 4);
        const float4 xv = *reinterpret_cast<const float4*>(x + (size_t)(r0 + r) * ALG_DIM + 4 * c);
        const float4 yv = *reinterpret_cast<const float4*>(y + (size_t)(r0 + r) * ALG_DIM + 4 * c);
        int b = (4 * c) * ROWS + r;
        xs[b] = xv.x; xs[b + ROWS] = xv.y; xs[b + 2 * ROWS] = xv.z; xs[b + 3 * ROWS] = xv.w;
        ys[b] = yv.x; ys[b + ROWS] = yv.y; ys[b + 2 * ROWS] = yv.z; ys[b + 3 * ROWS] = yv.w;
    }
    __syncthreads();

    const int   P     = meta[0];             // uniform, multiple of 8
    const float alpha = alpha_p[0];
    const int   S     = tid >> 2;            // stream 0..63 (owns one bucket)
    const int   qo4   = (tid & 3) << 4;      // quad byte offset within a column

    const char* xsb = reinterpret_cast<const char*>(xs) + qo4;
    const char* ysb = reinterpret_cast<const char*>(ys) + qo4;

    if (S < KPB) {
        const int k = blockIdx.y * KPB + S;
        const uint4* tp = packed4 + (size_t)k * (P >> 1);

        float4 acc = make_float4(0.f, 0.f, 0.f, 0.f);
        uint4 A = tp[0], B = tp[1], C = tp[2], D = tp[3];   // 8 triples in flight

        for (int t = 0; t < P; t += 8) {
            const int nb = (t >> 1) + 4;
            uint4 E = tp[nb + 0];            // unconditional prefetch (slack-padded)
            uint4 F = tp[nb + 1];
            uint4 G = tp[nb + 2];
            uint4 H = tp[nb + 3];

#define BODY(PW, PC)                                                           \
            {                                                                  \
                const float4 xv = *reinterpret_cast<const float4*>(xsb + ((PW) & 0xFFFFu)); \
                const float4 yv = *reinterpret_cast<const float4*>(ysb + ((PW) >> 16));     \
                const float  cc = __uint_as_float(PC);                         \
                acc.x = fmaf(xv.x * yv.x, cc, acc.x);                          \
                acc.y = fmaf(xv.y * yv.y, cc, acc.y);                          \
                acc.z = fmaf(xv.z * yv.z, cc, acc.z);                          \
                acc.w = fmaf(xv.w * yv.w, cc, acc.w);                          \
            }
            BODY(A.x, A.y) BODY(A.z, A.w)
            BODY(B.x, B.y) BODY(B.z, B.w)
            BODY(C.x, C.y) BODY(C.z, C.w)
            BODY(D.x, D.y) BODY(D.z, D.w)
#undef BODY
            A = E; B = F; C = G; D = H;
        }

        const int rbase = r0 + ((tid & 3) << 2);
        out[(size_t)(rbase + 0) * ALG_DIM + k] = alpha * acc.x;
        out[(size_t)(rbase + 1) * ALG_DIM + k] = alpha * acc.y;
        out[(size_t)(rbase + 2) * ALG_DIM + k] = alpha * acc.z;
        out[(size_t)(rbase + 3) * ALG_DIM + k] = alpha * acc.w;
    }
}

// ---------- launch ----------

extern "C" void kernel_launch(void* const* d_in, const int* in_sizes, int n_in,
                              void* d_out, int out_size, void* d_ws, size_t ws_size,
                              hipStream_t stream) {
    const float* x      = (const float*)d_in[0];
    const float* y      = (const float*)d_in[1];
    const int*   idx_i  = (const int*)d_in[2];
    const int*   idx_j  = (const int*)d_in[3];
    const int*   idx_k  = (const int*)d_in[4];
    const float* coeff  = (const float*)d_in[5];
    const float* alpha  = (const float*)d_in[6];
    float*       out    = (float*)d_out;

    const int nnz   = in_sizes[2];
    const int batch = in_sizes[0] / ALG_DIM;

    // ws layout: [meta 16B][cnt 1KB][cursor 1KB][pad to 4KB][packedP 248*PMAX*8 + slack]
    char*  ws      = (char*)d_ws;
    int*   meta    = (int*)ws;
    int*   cnt     = (int*)(ws + 16);
    int*   cursor  = (int*)(ws + 16 + 1024);
    uint2* packedP = (uint2*)(ws + 4096);

    k_init   <<<1, 256, 0, stream>>>(cnt);
    k_count  <<<(nnz + 255) / 256, 256, 0, stream>>>(idx_k, cnt, nnz);
    k_meta   <<<1, 256, 0, stream>>>(cnt, meta, cursor);
    k_fill   <<<256, 256, 0, stream>>>(packedP, meta);
    k_scatter<<<(nnz + 255) / 256, 256, 0, stream>>>(idx_i, idx_j, idx_k, coeff,
                                                     cursor, packedP, meta, nnz);

    dim3 grid(batch / ROWS, KSPLIT);
    k_main<<<grid, 256, 0, stream>>>(x, y, (const uint4*)packedP, meta, alpha, out);
}

// Round 5
// 153.468 us; speedup vs baseline: 1.6075x; 1.1144x over previous
//
#include <hip/hip_runtime.h>

#define ALG_DIM 248
#define ROWS 16                    // rows per main-kernel block
#define KSPLIT 4
#define KPB 62                     // k-slots per block (248/4)
#define PMAX 1024                  // safety clamp for padded bucket length

// ---------- prep: bucket triples by idx_k into SIZE-SORTED padded slots ----------
// Slot p (sorted by bucket size, descending) holds bucket k = perm[p] at
// packedP[p*P .. p*P+P). Pad entries have coeff = 0. Index halves pre-scaled
// to LDS byte offsets: lo16 = i*64, hi16 = j*64 (64 B = column stride).
// Sorting makes the 16 streams of a wave own similar-sized buckets, so the
// wave-uniform trip count (= size of the wave's largest bucket) wastes ~5%
// instead of the ~32% a grid-uniform P wasted.

__global__ void k_init(int* __restrict__ cnt) {
    int t = threadIdx.x;
    if (t < ALG_DIM) cnt[t] = 0;
}

__global__ void k_count(const int* __restrict__ idx_k, int* __restrict__ cnt, int nnz) {
    int t = blockIdx.x * blockDim.x + threadIdx.x;
    if (t < nnz) atomicAdd(&cnt[idx_k[t]], 1);
}

// Single small block: Pmax, rank-sort (O(248^2)), slot bases & cursors.
__global__ void k_sort(const int* __restrict__ cnt, int* __restrict__ meta,
                       int* __restrict__ perm, int* __restrict__ ssz,
                       int* __restrict__ cursor, int* __restrict__ bbase) {
    __shared__ int sz[256];
    __shared__ int red[256];
    const int t = threadIdx.x;
    sz[t] = (t < ALG_DIM) ? cnt[t] : 0;
    __syncthreads();
    red[t] = sz[t];
    __syncthreads();
    for (int off = 128; off > 0; off >>= 1) {
        if (t < off) red[t] = max(red[t], red[t + off]);
        __syncthreads();
    }
    __shared__ int Ps;
    if (t == 0) {
        int P = (red[0] + 7) & ~7;
        P = max(P, 8);
        P = min(P, PMAX);
        meta[0] = P;
        Ps = P;
    }
    __syncthreads();
    if (t < ALG_DIM) {
        const int mysz = sz[t];
        int rank = 0;
        for (int k = 0; k < ALG_DIM; ++k) {
            int s2 = sz[k];
            rank += (s2 > mysz) || (s2 == mysz && k < t);   // unique ranks
        }
        perm[rank]  = t;           // slot -> original k
        ssz[rank]   = mysz;        // slot -> bucket size (descending)
        cursor[t]   = rank * Ps;   // original k -> write cursor (element idx)
        bbase[t]    = rank * Ps;   // original k -> slot base (for overflow guard)
    }
}

__global__ void k_fill(uint2* __restrict__ packedP, const int* __restrict__ meta) {
    int P = meta[0];
    int total = ALG_DIM * P + 8;             // +8 slack for tail over-read
    int stride = gridDim.x * blockDim.x;
    for (int t = blockIdx.x * blockDim.x + threadIdx.x; t < total; t += stride)
        packedP[t] = make_uint2(0u, 0u);     // byte offset 0 / coeff 0.0f
}

__global__ void k_scatter(const int* __restrict__ idx_i, const int* __restrict__ idx_j,
                          const int* __restrict__ idx_k, const float* __restrict__ coeff,
                          int* __restrict__ cursor, const int* __restrict__ bbase,
                          uint2* __restrict__ packedP, const int* __restrict__ meta,
                          int nnz) {
    int t = blockIdx.x * blockDim.x + threadIdx.x;
    if (t < nnz) {
        int k = idx_k[t];
        int P = meta[0];
        int pos = atomicAdd(&cursor[k], 1);
        if (pos < bbase[k] + P) {            // can only trip if P was clamped
            uint2 p;
            p.x = ((unsigned)idx_i[t] << 6) | ((unsigned)idx_j[t] << 22);
            p.y = __float_as_uint(coeff[t]);
            packedP[pos] = p;
        }
    }
}

// ---------- main: sorted-slot gather-multiply-accumulate ----------
// Block: 256 threads = 64 streams x 4 quad-lanes over 16 rows x 62 slots.
// LDS column-major xs[col*16 + row] (31 KB total -> 5 blocks/CU). Lane's
// 4-row gather = one ds_read_b128. Trip count is wave-uniform (size of the
// wave's largest bucket, slots sorted descending): no bounds checks, no
// cndmask in the loop; unconditional 8-triple-ahead prefetch.

__global__ __launch_bounds__(256, 5) void k_main(
    const float* __restrict__ x, const float* __restrict__ y,
    const uint4* __restrict__ packed4,       // packedP viewed as uint4 (2 triples)
    const int* __restrict__ meta, const int* __restrict__ perm,
    const int* __restrict__ ssz,
    const float* __restrict__ alpha_p, float* __restrict__ out)
{
    __shared__ __align__(16) float xs[ALG_DIM * ROWS];
    __shared__ __align__(16) float ys[ALG_DIM * ROWS];

    const int tid = threadIdx.x;
    const int r0  = blockIdx.x * ROWS;

    // Staging: lane reads float4 along a row (16 B aligned: 248 = 8*31 dwords),
    // writes 4 scalar LDS stores. r = u&15 is the FAST index -> per store
    // instruction bank = (16m + r) % 32, only 4-way aliasing (c in 4 values),
    // vs round 4's r-slow layout which gave ~60-way write conflicts.
    for (int u = tid; u < (ALG_DIM / 4) * ROWS; u += 256) {
        const int r = u & 15;
        const int c = u >> 4;                // 0..61
        const float4 xv = *reinterpret_cast<const float4*>(x + (size_t)(r0 + r) * ALG_DIM + 4 * c);
        const float4 yv = *reinterpret_cast<const float4*>(y + (size_t)(r0 + r) * ALG_DIM + 4 * c);
        const int b = (4 * c) * ROWS + r;
        xs[b] = xv.x; xs[b + ROWS] = xv.y; xs[b + 2 * ROWS] = xv.z; xs[b + 3 * ROWS] = xv.w;
        ys[b] = yv.x; ys[b + ROWS] = yv.y; ys[b + 2 * ROWS] = yv.z; ys[b + 3 * ROWS] = yv.w;
    }
    __syncthreads();

    const int   P     = meta[0];             // slot stride (elements), mult of 8
    const float alpha = alpha_p[0];
    const int   S     = tid >> 2;            // stream 0..63 (owns one slot)
    const int   qo4   = (tid & 3) << 4;      // quad byte offset within a column

    const char* xsb = reinterpret_cast<const char*>(xs) + qo4;
    const char* ysb = reinterpret_cast<const char*>(ys) + qo4;

    if (S < KPB) {
        const int p = blockIdx.y * KPB + S;  // my sorted slot
        const int k = perm[p];               // my output column

        // wave-uniform trip: slots sorted descending => first slot of the wave
        // is the wave's max bucket size.
        const int pw   = blockIdx.y * KPB + ((tid >> 6) << 4);
        const int trip = __builtin_amdgcn_readfirstlane((ssz[pw] + 7) & ~7);

        const uint4* tp = packed4 + (size_t)p * (P >> 1);

        float4 acc = make_float4(0.f, 0.f, 0.f, 0.f);
        uint4 A = tp[0], B = tp[1], C = tp[2], D = tp[3];   // 8 triples in flight

        for (int t = 0; t < trip; t += 8) {
            const int nb = (t >> 1) + 4;
            uint4 E = tp[nb + 0];            // unconditional prefetch (slack-padded)
            uint4 F = tp[nb + 1];
            uint4 G = tp[nb + 2];
            uint4 H = tp[nb + 3];

#define BODY(PW, PC)                                                           \
            {                                                                  \
                const float4 xv = *reinterpret_cast<const float4*>(xsb + ((PW) & 0xFFFFu)); \
                const float4 yv = *reinterpret_cast<const float4*>(ysb + ((PW) >> 16));     \
                const float  cc = __uint_as_float(PC);                         \
                acc.x = fmaf(xv.x * yv.x, cc, acc.x);                          \
                acc.y = fmaf(xv.y * yv.y, cc, acc.y);                          \
                acc.z = fmaf(xv.z * yv.z, cc, acc.z);                          \
                acc.w = fmaf(xv.w * yv.w, cc, acc.w);                          \
            }
            BODY(A.x, A.y) BODY(A.z, A.w)
            BODY(B.x, B.y) BODY(B.z, B.w)
            BODY(C.x, C.y) BODY(C.z, C.w)
            BODY(D.x, D.y) BODY(D.z, D.w)
#undef BODY
            A = E; B = F; C = G; D = H;
        }

        const int rbase = r0 + ((tid & 3) << 2);
        out[(size_t)(rbase + 0) * ALG_DIM + k] = alpha * acc.x;
        out[(size_t)(rbase + 1) * ALG_DIM + k] = alpha * acc.y;
        out[(size_t)(rbase + 2) * ALG_DIM + k] = alpha * acc.z;
        out[(size_t)(rbase + 3) * ALG_DIM + k] = alpha * acc.w;
    }
}

// ---------- launch ----------

extern "C" void kernel_launch(void* const* d_in, const int* in_sizes, int n_in,
                              void* d_out, int out_size, void* d_ws, size_t ws_size,
                              hipStream_t stream) {
    const float* x      = (const float*)d_in[0];
    const float* y      = (const float*)d_in[1];
    const int*   idx_i  = (const int*)d_in[2];
    const int*   idx_j  = (const int*)d_in[3];
    const int*   idx_k  = (const int*)d_in[4];
    const float* coeff  = (const float*)d_in[5];
    const float* alpha  = (const float*)d_in[6];
    float*       out    = (float*)d_out;

    const int nnz   = in_sizes[2];
    const int batch = in_sizes[0] / ALG_DIM;

    // ws: [meta 16B][cnt 1K][cursor 1K][perm 1K][ssz 1K][bbase 1K][pad->8K][packedP]
    char*  ws      = (char*)d_ws;
    int*   meta    = (int*)ws;
    int*   cnt     = (int*)(ws + 16);
    int*   cursor  = (int*)(ws + 16 + 1024);
    int*   perm    = (int*)(ws + 16 + 2 * 1024);
    int*   ssz     = (int*)(ws + 16 + 3 * 1024);
    int*   bbase   = (int*)(ws + 16 + 4 * 1024);
    uint2* packedP = (uint2*)(ws + 8192);

    k_init   <<<1, 256, 0, stream>>>(cnt);
    k_count  <<<(nnz + 255) / 256, 256, 0, stream>>>(idx_k, cnt, nnz);
    k_sort   <<<1, 256, 0, stream>>>(cnt, meta, perm, ssz, cursor, bbase);
    k_fill   <<<256, 256, 0, stream>>>(packedP, meta);
    k_scatter<<<(nnz + 255) / 256, 256, 0, stream>>>(idx_i, idx_j, idx_k, coeff,
                                                     cursor, bbase, packedP, meta, nnz);

    dim3 grid(batch / ROWS, KSPLIT);
    k_main<<<grid, 256, 0, stream>>>(x, y, (const uint4*)packedP, meta, perm, ssz,
                                     alpha, out);
}